// Round 3
// baseline (148.480 us; speedup 1.0000x reference)
//
#include <hip/hip_runtime.h>

#define T_SEQ 2048
#define C_DIM 1024
#define H_DIM 64
#define B_DIM 8
#define NROW (B_DIM * T_SEQ)  // 16384

typedef __attribute__((ext_vector_type(8))) short short8;
typedef __attribute__((ext_vector_type(4))) float f32x4;

__device__ __forceinline__ short f2bf(float f) {
  unsigned u = __builtin_bit_cast(unsigned, f);
  u += 0x7fffu + ((u >> 16) & 1u);  // round-to-nearest-even
  return (short)(u >> 16);
}

// ---------------------------------------------------------------------------
// P: Wt2 in FRAGMENT-LINEAR order (unchanged).
// ---------------------------------------------------------------------------
__global__ __launch_bounds__(256) void w_prep(
    const float* __restrict__ Wq, const float* __restrict__ Wk,
    const float* __restrict__ Wv, short* __restrict__ Wt2) {
  const int unit = blockIdx.x * 256 + threadIdx.x;  // 0..24575
  const int lane = unit & 63;
  const int t = unit >> 6;
  const int kh = t & 3;
  const int g = t >> 2;    // kc*12 + ntg
  const int ntg = g % 12;
  const int kc = g / 12;
  const int n16 = lane & 15, quad = lane >> 4;
  const int mat = ntg >> 2;
  const int h = (ntg & 3) * 16 + n16;
  const int kb = kc * 128 + kh * 32 + quad * 8;
  const float* W = (mat == 0) ? Wq : (mat == 1 ? Wk : Wv);
  short8 v;
#pragma unroll
  for (int e = 0; e < 8; ++e) v[e] = f2bf(W[(size_t)(kb + e) * H_DIM + h]);
  *(short8*)(Wt2 + (size_t)unit * 8) = v;
}

// LDS address (in shorts) for A frag unit (tile, kh, quad, n16); XOR-swizzled.
__device__ __forceinline__ int lds_addr(int tile, int kh, int qd, int nn) {
  return tile * 2048 + kh * 512 + (qd * 16 + (nn ^ ((kh * 4 + qd) & 7))) * 8;
}

// ---------------------------------------------------------------------------
// K1: QKV projection (byte-identical -- at its structural/HBM bound).
// ---------------------------------------------------------------------------
__global__ __launch_bounds__(256, 2) void qkv_gemm(
    const float* __restrict__ x, const short* __restrict__ Wt2,
    short* __restrict__ q, short* __restrict__ k, short* __restrict__ vt) {
  __shared__ __align__(16) short As[2][4096];  // 2 x 8 KB (32 x 128 bf16)
  const int tid = threadIdx.x;
  const int w = tid >> 6, lane = tid & 63;
  const int n16 = lane & 15, quad = lane >> 4;
  const int row0 = blockIdx.x * 32;

  f32x4 acc[2][3];
#pragma unroll
  for (int mt = 0; mt < 2; ++mt)
#pragma unroll
    for (int ln = 0; ln < 3; ++ln) acc[mt][ln] = (f32x4){0.f, 0.f, 0.f, 0.f};

  const int u20 = tid, u21 = 256 + tid;
  const int sr0 = u20 >> 4, f0 = u20 & 15;
  const int sr1 = u21 >> 4, f1 = u21 & 15;
  const float* ap0 = x + (size_t)(row0 + sr0) * C_DIM + f0 * 8;
  const float* ap1 = x + (size_t)(row0 + sr1) * C_DIM + f1 * 8;
  const int soff0 = lds_addr(sr0 >> 4, f0 >> 2, f0 & 3, sr0 & 15);
  const int soff1 = lds_addr(sr1 >> 4, f1 >> 2, f1 & 3, sr1 & 15);

  int swz[4];
#pragma unroll
  for (int kh = 0; kh < 4; ++kh)
    swz[kh] = (quad * 16 + (n16 ^ ((kh * 4 + quad) & 7))) * 8;

  const short* bbase = Wt2 + (size_t)(w * 3) * 2048 + (size_t)lane * 8;

  float4 astg[2][4];
  short8 bfr[12];

#define STAGE_A(d, p)                                      \
  {                                                        \
    short8 av0, av1;                                       \
    _Pragma("unroll") for (int e = 0; e < 4; ++e) {        \
      av0[e] = f2bf(((const float*)&astg[d][0])[e]);       \
      av0[e + 4] = f2bf(((const float*)&astg[d][1])[e]);   \
      av1[e] = f2bf(((const float*)&astg[d][2])[e]);       \
      av1[e + 4] = f2bf(((const float*)&astg[d][3])[e]);   \
    }                                                      \
    *(short8*)(&As[p][0] + soff0) = av0;                   \
    *(short8*)(&As[p][0] + soff1) = av1;                   \
  }

  astg[0][0] = *(const float4*)(ap0);
  astg[0][1] = *(const float4*)(ap0 + 4);
  astg[0][2] = *(const float4*)(ap1);
  astg[0][3] = *(const float4*)(ap1 + 4);
  astg[1][0] = *(const float4*)(ap0 + 128);
  astg[1][1] = *(const float4*)(ap0 + 132);
  astg[1][2] = *(const float4*)(ap1 + 128);
  astg[1][3] = *(const float4*)(ap1 + 132);
#pragma unroll
  for (int ln = 0; ln < 3; ++ln)
#pragma unroll
    for (int kh = 0; kh < 4; ++kh)
      bfr[ln * 4 + kh] = *(const short8*)(bbase + ln * 2048 + kh * 512);
  STAGE_A(0, 0);
  asm volatile("s_waitcnt lgkmcnt(0)" ::: "memory");
  __builtin_amdgcn_sched_barrier(0);
  __builtin_amdgcn_s_barrier();
  __builtin_amdgcn_sched_barrier(0);

#pragma unroll
  for (int kc = 0; kc < 8; ++kc) {
    const short* asb = &As[kc & 1][0];
#pragma unroll
    for (int kh = 0; kh < 4; ++kh) {
      const short8 a0 = *(const short8*)(asb + kh * 512 + swz[kh]);
      const short8 a1 = *(const short8*)(asb + 2048 + kh * 512 + swz[kh]);
#pragma unroll
      for (int ln = 0; ln < 3; ++ln) {
        acc[0][ln] = __builtin_amdgcn_mfma_f32_16x16x32_bf16(
            a0, bfr[ln * 4 + kh], acc[0][ln], 0, 0, 0);
        acc[1][ln] = __builtin_amdgcn_mfma_f32_16x16x32_bf16(
            a1, bfr[ln * 4 + kh], acc[1][ln], 0, 0, 0);
      }
    }
    if (kc < 7) {
      const short* bc = bbase + (size_t)(kc + 1) * 24576;
#pragma unroll
      for (int ln = 0; ln < 3; ++ln)
#pragma unroll
        for (int kh = 0; kh < 4; ++kh)
          bfr[ln * 4 + kh] = *(const short8*)(bc + ln * 2048 + kh * 512);
      if (kc < 6) {
        astg[kc & 1][0] = *(const float4*)(ap0 + (kc + 2) * 128);
        astg[kc & 1][1] = *(const float4*)(ap0 + (kc + 2) * 128 + 4);
        astg[kc & 1][2] = *(const float4*)(ap1 + (kc + 2) * 128);
        astg[kc & 1][3] = *(const float4*)(ap1 + (kc + 2) * 128 + 4);
      }
      STAGE_A((kc + 1) & 1, (kc + 1) & 1);
      asm volatile("s_waitcnt lgkmcnt(0)" ::: "memory");
      __builtin_amdgcn_sched_barrier(0);
      __builtin_amdgcn_s_barrier();
      __builtin_amdgcn_sched_barrier(0);
    }
  }
#undef STAGE_A

  const int b = row0 >> 11;
#pragma unroll
  for (int mt = 0; mt < 2; ++mt)
#pragma unroll
    for (int ln = 0; ln < 3; ++ln) {
      const int ntg = w * 3 + ln;
      const int mat = ntg >> 2;
      const int cl = (ntg & 3) * 16 + n16;
#pragma unroll
      for (int r = 0; r < 4; ++r) {
        const int row = row0 + mt * 16 + quad * 4 + r;
        const float v = acc[mt][ln][r];
        if (mat == 0)
          q[(size_t)row * H_DIM + cl] = f2bf(v * 0.125f);
        else if (mat == 1)
          k[(size_t)row * H_DIM + cl] = f2bf(v);
        else
          vt[((size_t)b * H_DIM + cl) * T_SEQ + (row & (T_SEQ - 1))] = f2bf(v);
      }
    }
}

// ---------------------------------------------------------------------------
// K2: paired-tile flash attention + SOFTWARE-PIPELINED K/V loads.
// Change vs previous round: bk/bv are double-buffered in registers and iter
// jt+4's 16 global loads are issued right after iter jt's QK MFMAs consume
// the current K -- their L2 latency (~200-400 cy) hides under exp/pack/PV
// and the next QK instead of stalling the serial chain every iteration.
// Per-row arithmetic order unchanged (same jt%4==w partition) -> absmax
// bit-identical.  ~230 VGPR peak, launch_bounds(256,2) keeps 2 blocks/CU.
// ---------------------------------------------------------------------------
__global__ __launch_bounds__(256, 2) void attn_mfma(
    const short* __restrict__ q, const short* __restrict__ k,
    const short* __restrict__ vt, float* __restrict__ out) {
  __shared__ __align__(16) short pbuf[4][2048];    // per-wave: A | B
  __shared__ __align__(16) float oshare[3][2048];  // A | B
  __shared__ __align__(16) float lshare[3][512];   // A | B
  const int tid = threadIdx.x;
  const int w = tid >> 6;
  const int lane = tid & 63;
  const int n16 = lane & 15, quad = lane >> 4;
  const int b = blockIdx.x & 7;     // b == XCD slot -> K/V L2-resident
  const int pa = blockIdx.x >> 3;   // 0..63
  const int r0a = pa * 16;          // low tile rows
  const int r0b = (127 - pa) * 16;  // high tile rows

  const short* kb = k + (size_t)b * T_SEQ * H_DIM;
  const short* vb = vt + (size_t)b * H_DIM * T_SEQ;
  const short* qpa = q + ((size_t)b * T_SEQ + r0a) * H_DIM;
  const short* qpb = q + ((size_t)b * T_SEQ + r0b) * H_DIM;

  short8 aqA[2], aqB[2];
  aqA[0] = *(const short8*)(qpa + (size_t)n16 * H_DIM + quad * 8);
  aqA[1] = *(const short8*)(qpa + (size_t)n16 * H_DIM + 32 + quad * 8);
  aqB[0] = *(const short8*)(qpb + (size_t)n16 * H_DIM + quad * 8);
  aqB[1] = *(const short8*)(qpb + (size_t)n16 * H_DIM + 32 + quad * 8);

  f32x4 OA[4], OB[4];
#pragma unroll
  for (int i = 0; i < 4; ++i) {
    OA[i] = (f32x4){0.f, 0.f, 0.f, 0.f};
    OB[i] = (f32x4){0.f, 0.f, 0.f, 0.f};
  }
  float lsA[4] = {0.f, 0.f, 0.f, 0.f};
  float lsB[4] = {0.f, 0.f, 0.f, 0.f};

  const int nj = (r0b + 16 + 63) >> 6;   // j-tiles of 64 for the high tile
  const int njA = (r0a + 16 + 63) >> 6;  // j-tiles needed by the low tile

  short8 bk0[4][2], bv0[4][2], bk1[4][2], bv1[4][2];

#define LOADK(BK, J0)                                                        \
  _Pragma("unroll") for (int nt = 0; nt < 4; ++nt) {                         \
    const short* kp = kb + (size_t)((J0) + nt * 16 + n16) * H_DIM + quad * 8; \
    BK[nt][0] = *(const short8*)kp;                                          \
    BK[nt][1] = *(const short8*)(kp + 32);                                   \
  }
#define LOADV(BV, J0)                                                        \
  _Pragma("unroll") for (int ht = 0; ht < 4; ++ht)                           \
  _Pragma("unroll") for (int kh = 0; kh < 2; ++kh)                           \
      BV[ht][kh] = *(const short8*)(vb + (size_t)(ht * 16 + n16) * T_SEQ +   \
                                    (J0) + kh * 32 + quad * 8);

#define DOITER(BK, BV, JT, ...)                                               \
  {                                                                           \
    const int j0 = (JT) * 64;                                                 \
    const bool actA = ((JT) < njA);                                           \
    f32x4 sB[4];                                                              \
    _Pragma("unroll") for (int nt = 0; nt < 4; ++nt) {                        \
      f32x4 z = (f32x4){0.f, 0.f, 0.f, 0.f};                                  \
      z = __builtin_amdgcn_mfma_f32_16x16x32_bf16(aqB[0], BK[nt][0], z, 0, 0, 0); \
      z = __builtin_amdgcn_mfma_f32_16x16x32_bf16(aqB[1], BK[nt][1], z, 0, 0, 0); \
      sB[nt] = z;                                                             \
    }                                                                         \
    f32x4 sA[4];                                                              \
    if (actA) {                                                               \
      _Pragma("unroll") for (int nt = 0; nt < 4; ++nt) {                      \
        f32x4 z = (f32x4){0.f, 0.f, 0.f, 0.f};                                \
        z = __builtin_amdgcn_mfma_f32_16x16x32_bf16(aqA[0], BK[nt][0], z, 0, 0, 0); \
        z = __builtin_amdgcn_mfma_f32_16x16x32_bf16(aqA[1], BK[nt][1], z, 0, 0, 0); \
        sA[nt] = z;                                                           \
      }                                                                       \
    }                                                                         \
    __VA_ARGS__ /* prefetch next iter's K/V: latency hides under exp+PV */    \
    const bool fullB = (j0 + 64 <= r0b);                                      \
    _Pragma("unroll") for (int nt = 0; nt < 4; ++nt) {                        \
      const int base = (nt >> 1) * 512 +                                      \
                       ((((nt & 1) << 1) | (n16 >> 3)) * 128) + (n16 & 7);    \
      _Pragma("unroll") for (int r = 0; r < 4; ++r) {                         \
        float p;                                                              \
        if (fullB) {                                                          \
          p = __expf(sB[nt][r]);                                              \
        } else {                                                              \
          const int j = j0 + nt * 16 + n16;                                   \
          const int row = r0b + quad * 4 + r;                                 \
          p = (j <= row) ? __expf(sB[nt][r]) : 0.f;                           \
        }                                                                     \
        lsB[r] += p;                                                          \
        pbuf[w][1024 + base + (quad * 4 + r) * 8] = f2bf(p);                  \
      }                                                                       \
    }                                                                         \
    if (actA) {                                                               \
      const bool fullA = (j0 + 64 <= r0a);                                    \
      _Pragma("unroll") for (int nt = 0; nt < 4; ++nt) {                      \
        const int base = (nt >> 1) * 512 +                                    \
                         ((((nt & 1) << 1) | (n16 >> 3)) * 128) + (n16 & 7);  \
        _Pragma("unroll") for (int r = 0; r < 4; ++r) {                       \
          float p;                                                            \
          if (fullA) {                                                        \
            p = __expf(sA[nt][r]);                                            \
          } else {                                                            \
            const int j = j0 + nt * 16 + n16;                                 \
            const int row = r0a + quad * 4 + r;                               \
            p = (j <= row) ? __expf(sA[nt][r]) : 0.f;                         \
          }                                                                   \
          lsA[r] += p;                                                        \
          pbuf[w][base + (quad * 4 + r) * 8] = f2bf(p);                       \
        }                                                                     \
      }                                                                       \
    }                                                                         \
    const short8 apB0 = *(const short8*)(&pbuf[w][1024] + lane * 8);          \
    const short8 apB1 = *(const short8*)(&pbuf[w][1536] + lane * 8);          \
    _Pragma("unroll") for (int ht = 0; ht < 4; ++ht) {                        \
      OB[ht] = __builtin_amdgcn_mfma_f32_16x16x32_bf16(apB0, BV[ht][0], OB[ht], 0, 0, 0); \
      OB[ht] = __builtin_amdgcn_mfma_f32_16x16x32_bf16(apB1, BV[ht][1], OB[ht], 0, 0, 0); \
    }                                                                         \
    if (actA) {                                                               \
      const short8 apA0 = *(const short8*)(&pbuf[w][0] + lane * 8);           \
      const short8 apA1 = *(const short8*)(&pbuf[w][512] + lane * 8);         \
      _Pragma("unroll") for (int ht = 0; ht < 4; ++ht) {                      \
        OA[ht] = __builtin_amdgcn_mfma_f32_16x16x32_bf16(apA0, BV[ht][0], OA[ht], 0, 0, 0); \
        OA[ht] = __builtin_amdgcn_mfma_f32_16x16x32_bf16(apA1, BV[ht][1], OA[ht], 0, 0, 0); \
      }                                                                       \
    }                                                                         \
  }

  // prologue: load first tile's K/V
  {
    const int j00 = w * 64;
    LOADK(bk0, j00);
    LOADV(bv0, j00);
  }
  for (int jt = w; jt < nj; jt += 8) {
    const int jB = jt + 4;
    DOITER(bk0, bv0, jt, if (jB < nj) {
      LOADK(bk1, jB * 64);
      LOADV(bv1, jB * 64);
    })
    if (jB < nj) {
      const int jC = jt + 8;
      DOITER(bk1, bv1, jB, if (jC < nj) {
        LOADK(bk0, jC * 64);
        LOADV(bv0, jC * 64);
      })
    }
  }
#undef DOITER
#undef LOADK
#undef LOADV

  // --- cross-wave reduction (unchanged) ---
  if (w != 0) {
#pragma unroll
    for (int ht = 0; ht < 4; ++ht)
#pragma unroll
      for (int r = 0; r < 4; ++r) {
        oshare[w - 1][(ht * 4 + r) * 64 + lane] = OA[ht][r];
        oshare[w - 1][1024 + (ht * 4 + r) * 64 + lane] = OB[ht][r];
      }
#pragma unroll
    for (int r = 0; r < 4; ++r) {
      lshare[w - 1][r * 64 + lane] = lsA[r];
      lshare[w - 1][256 + r * 64 + lane] = lsB[r];
    }
  }
  __syncthreads();
  if (w == 0) {
#pragma unroll
    for (int ht = 0; ht < 4; ++ht)
#pragma unroll
      for (int r = 0; r < 4; ++r) {
        float a = OA[ht][r], bb = OB[ht][r];
#pragma unroll
        for (int ow = 0; ow < 3; ++ow) {
          a += oshare[ow][(ht * 4 + r) * 64 + lane];
          bb += oshare[ow][1024 + (ht * 4 + r) * 64 + lane];
        }
        OA[ht][r] = a;
        OB[ht][r] = bb;
      }
#pragma unroll
    for (int r = 0; r < 4; ++r) {
      float va = lsA[r], vb2 = lsB[r];
#pragma unroll
      for (int ow = 0; ow < 3; ++ow) {
        va += lshare[ow][r * 64 + lane];
        vb2 += lshare[ow][256 + r * 64 + lane];
      }
      va += __shfl_xor(va, 1);
      va += __shfl_xor(va, 2);
      va += __shfl_xor(va, 4);
      va += __shfl_xor(va, 8);
      vb2 += __shfl_xor(vb2, 1);
      vb2 += __shfl_xor(vb2, 2);
      vb2 += __shfl_xor(vb2, 4);
      vb2 += __shfl_xor(vb2, 8);
      lsA[r] = va;
      lsB[r] = vb2;
    }
#pragma unroll
    for (int ht = 0; ht < 4; ++ht)
#pragma unroll
      for (int r = 0; r < 4; ++r) {
        out[((size_t)b * T_SEQ + r0a + quad * 4 + r) * H_DIM + ht * 16 + n16] =
            OA[ht][r] / lsA[r];
        out[((size_t)b * T_SEQ + r0b + quad * 4 + r) * H_DIM + ht * 16 + n16] =
            OB[ht][r] / lsB[r];
      }
  }
}

extern "C" void kernel_launch(void* const* d_in, const int* in_sizes, int n_in,
                              void* d_out, int out_size, void* d_ws,
                              size_t ws_size, hipStream_t stream) {
  const float* x = (const float*)d_in[0];
  const float* Wq = (const float*)d_in[1];
  const float* Wk = (const float*)d_in[2];
  const float* Wv = (const float*)d_in[3];

  char* ws = (char*)d_ws;
  short* Wt = (short*)ws;                       // 384 KB (fragment-linear)
  short* q = (short*)(ws + 3 * 64 * 1024 * 2);  // 2 MB each
  short* kk = (short*)(ws + 3 * 64 * 1024 * 2 + 2097152);
  short* vt = (short*)(ws + 3 * 64 * 1024 * 2 + 2 * 2097152);

  w_prep<<<96, 256, 0, stream>>>(Wq, Wk, Wv, Wt);
  qkv_gemm<<<NROW / 32, 256, 0, stream>>>(x, Wt, q, kk, vt);
  attn_mfma<<<B_DIM * (T_SEQ / 32), 256, 0, stream>>>(q, kk, vt, (float*)d_out);
}

// Round 4
// 143.274 us; speedup vs baseline: 1.0363x; 1.0363x over previous
//
#include <hip/hip_runtime.h>

#define T_SEQ 2048
#define C_DIM 1024
#define H_DIM 64
#define B_DIM 8
#define NROW (B_DIM * T_SEQ)  // 16384
#define PH 6                  // j-phase split of each paired tile

typedef __attribute__((ext_vector_type(8))) short short8;
typedef __attribute__((ext_vector_type(4))) float f32x4;

__device__ __forceinline__ short f2bf(float f) {
  unsigned u = __builtin_bit_cast(unsigned, f);
  u += 0x7fffu + ((u >> 16) & 1u);  // round-to-nearest-even
  return (short)(u >> 16);
}

// ---------------------------------------------------------------------------
// P: Wt2 in FRAGMENT-LINEAR order (unchanged).
// ---------------------------------------------------------------------------
__global__ __launch_bounds__(256) void w_prep(
    const float* __restrict__ Wq, const float* __restrict__ Wk,
    const float* __restrict__ Wv, short* __restrict__ Wt2) {
  const int unit = blockIdx.x * 256 + threadIdx.x;  // 0..24575
  const int lane = unit & 63;
  const int t = unit >> 6;
  const int kh = t & 3;
  const int g = t >> 2;    // kc*12 + ntg
  const int ntg = g % 12;
  const int kc = g / 12;
  const int n16 = lane & 15, quad = lane >> 4;
  const int mat = ntg >> 2;
  const int h = (ntg & 3) * 16 + n16;
  const int kb = kc * 128 + kh * 32 + quad * 8;
  const float* W = (mat == 0) ? Wq : (mat == 1 ? Wk : Wv);
  short8 v;
#pragma unroll
  for (int e = 0; e < 8; ++e) v[e] = f2bf(W[(size_t)(kb + e) * H_DIM + h]);
  *(short8*)(Wt2 + (size_t)unit * 8) = v;
}

// LDS address (in shorts) for A frag unit (tile, kh, quad, n16); XOR-swizzled.
__device__ __forceinline__ int lds_addr(int tile, int kh, int qd, int nn) {
  return tile * 2048 + kh * 512 + (qd * 16 + (nn ^ ((kh * 4 + qd) & 7))) * 8;
}

// ---------------------------------------------------------------------------
// K1: QKV projection (byte-identical -- at its structural/HBM bound).
// ---------------------------------------------------------------------------
__global__ __launch_bounds__(256, 2) void qkv_gemm(
    const float* __restrict__ x, const short* __restrict__ Wt2,
    short* __restrict__ q, short* __restrict__ k, short* __restrict__ vt) {
  __shared__ __align__(16) short As[2][4096];  // 2 x 8 KB (32 x 128 bf16)
  const int tid = threadIdx.x;
  const int w = tid >> 6, lane = tid & 63;
  const int n16 = lane & 15, quad = lane >> 4;
  const int row0 = blockIdx.x * 32;

  f32x4 acc[2][3];
#pragma unroll
  for (int mt = 0; mt < 2; ++mt)
#pragma unroll
    for (int ln = 0; ln < 3; ++ln) acc[mt][ln] = (f32x4){0.f, 0.f, 0.f, 0.f};

  const int u20 = tid, u21 = 256 + tid;
  const int sr0 = u20 >> 4, f0 = u20 & 15;
  const int sr1 = u21 >> 4, f1 = u21 & 15;
  const float* ap0 = x + (size_t)(row0 + sr0) * C_DIM + f0 * 8;
  const float* ap1 = x + (size_t)(row0 + sr1) * C_DIM + f1 * 8;
  const int soff0 = lds_addr(sr0 >> 4, f0 >> 2, f0 & 3, sr0 & 15);
  const int soff1 = lds_addr(sr1 >> 4, f1 >> 2, f1 & 3, sr1 & 15);

  int swz[4];
#pragma unroll
  for (int kh = 0; kh < 4; ++kh)
    swz[kh] = (quad * 16 + (n16 ^ ((kh * 4 + quad) & 7))) * 8;

  const short* bbase = Wt2 + (size_t)(w * 3) * 2048 + (size_t)lane * 8;

  float4 astg[2][4];
  short8 bfr[12];

#define STAGE_A(d, p)                                      \
  {                                                        \
    short8 av0, av1;                                       \
    _Pragma("unroll") for (int e = 0; e < 4; ++e) {        \
      av0[e] = f2bf(((const float*)&astg[d][0])[e]);       \
      av0[e + 4] = f2bf(((const float*)&astg[d][1])[e]);   \
      av1[e] = f2bf(((const float*)&astg[d][2])[e]);       \
      av1[e + 4] = f2bf(((const float*)&astg[d][3])[e]);   \
    }                                                      \
    *(short8*)(&As[p][0] + soff0) = av0;                   \
    *(short8*)(&As[p][0] + soff1) = av1;                   \
  }

  astg[0][0] = *(const float4*)(ap0);
  astg[0][1] = *(const float4*)(ap0 + 4);
  astg[0][2] = *(const float4*)(ap1);
  astg[0][3] = *(const float4*)(ap1 + 4);
  astg[1][0] = *(const float4*)(ap0 + 128);
  astg[1][1] = *(const float4*)(ap0 + 132);
  astg[1][2] = *(const float4*)(ap1 + 128);
  astg[1][3] = *(const float4*)(ap1 + 132);
#pragma unroll
  for (int ln = 0; ln < 3; ++ln)
#pragma unroll
    for (int kh = 0; kh < 4; ++kh)
      bfr[ln * 4 + kh] = *(const short8*)(bbase + ln * 2048 + kh * 512);
  STAGE_A(0, 0);
  asm volatile("s_waitcnt lgkmcnt(0)" ::: "memory");
  __builtin_amdgcn_sched_barrier(0);
  __builtin_amdgcn_s_barrier();
  __builtin_amdgcn_sched_barrier(0);

#pragma unroll
  for (int kc = 0; kc < 8; ++kc) {
    const short* asb = &As[kc & 1][0];
#pragma unroll
    for (int kh = 0; kh < 4; ++kh) {
      const short8 a0 = *(const short8*)(asb + kh * 512 + swz[kh]);
      const short8 a1 = *(const short8*)(asb + 2048 + kh * 512 + swz[kh]);
#pragma unroll
      for (int ln = 0; ln < 3; ++ln) {
        acc[0][ln] = __builtin_amdgcn_mfma_f32_16x16x32_bf16(
            a0, bfr[ln * 4 + kh], acc[0][ln], 0, 0, 0);
        acc[1][ln] = __builtin_amdgcn_mfma_f32_16x16x32_bf16(
            a1, bfr[ln * 4 + kh], acc[1][ln], 0, 0, 0);
      }
    }
    if (kc < 7) {
      const short* bc = bbase + (size_t)(kc + 1) * 24576;
#pragma unroll
      for (int ln = 0; ln < 3; ++ln)
#pragma unroll
        for (int kh = 0; kh < 4; ++kh)
          bfr[ln * 4 + kh] = *(const short8*)(bc + ln * 2048 + kh * 512);
      if (kc < 6) {
        astg[kc & 1][0] = *(const float4*)(ap0 + (kc + 2) * 128);
        astg[kc & 1][1] = *(const float4*)(ap0 + (kc + 2) * 128 + 4);
        astg[kc & 1][2] = *(const float4*)(ap1 + (kc + 2) * 128);
        astg[kc & 1][3] = *(const float4*)(ap1 + (kc + 2) * 128 + 4);
      }
      STAGE_A((kc + 1) & 1, (kc + 1) & 1);
      asm volatile("s_waitcnt lgkmcnt(0)" ::: "memory");
      __builtin_amdgcn_sched_barrier(0);
      __builtin_amdgcn_s_barrier();
      __builtin_amdgcn_sched_barrier(0);
    }
  }
#undef STAGE_A

  const int b = row0 >> 11;
#pragma unroll
  for (int mt = 0; mt < 2; ++mt)
#pragma unroll
    for (int ln = 0; ln < 3; ++ln) {
      const int ntg = w * 3 + ln;
      const int mat = ntg >> 2;
      const int cl = (ntg & 3) * 16 + n16;
#pragma unroll
      for (int r = 0; r < 4; ++r) {
        const int row = row0 + mt * 16 + quad * 4 + r;
        const float v = acc[mt][ln][r];
        if (mat == 0)
          q[(size_t)row * H_DIM + cl] = f2bf(v * 0.125f);
        else if (mat == 1)
          k[(size_t)row * H_DIM + cl] = f2bf(v);
        else
          vt[((size_t)b * H_DIM + cl) * T_SEQ + (row & (T_SEQ - 1))] = f2bf(v);
      }
    }
}

// ---------------------------------------------------------------------------
// K2a: partial paired-tile flash attention.  ONE WAVE per block; each block
// owns (batch b, pair pa, phase ph) and processes j-tiles jt = ph, ph+PH, ...
// 3072 blocks = 3072 waves = 12 waves/CU (launch_bounds(64,3) pins 3/SIMD;
// natural VGPR ~160 fits -- R3's spills came from a 128 cap, removed here).
// No cross-wave reduction, no syncthreads, 4 KB LDS.  V loads issued at iter
// top (latency hides under QK+exp).  Per-row math order identical to before.
// Writes phase-partial O (fp32) and lsum to workspace for K2b to combine.
// ---------------------------------------------------------------------------
__global__ __launch_bounds__(64, 3) void attn_part(
    const short* __restrict__ q, const short* __restrict__ k,
    const short* __restrict__ vt, float* __restrict__ Opart,
    float* __restrict__ lpart) {
  __shared__ __align__(16) short pbuf[2048];  // tile A: [0..1023], B: [1024..]
  const int lane = threadIdx.x;
  const int n16 = lane & 15, quad = lane >> 4;
  const int blk = blockIdx.x;
  const int b = blk & 7;           // batch == XCD slot -> K/V L2-resident
  const int ph = (blk >> 3) % PH;  // j-phase
  const int pa = blk / (8 * PH);   // 0..63
  const int r0a = pa * 16;         // low tile rows
  const int r0b = (127 - pa) * 16; // high tile rows

  const short* kb = k + (size_t)b * T_SEQ * H_DIM;
  const short* vb = vt + (size_t)b * H_DIM * T_SEQ;
  const short* qpa = q + ((size_t)b * T_SEQ + r0a) * H_DIM;
  const short* qpb = q + ((size_t)b * T_SEQ + r0b) * H_DIM;

  short8 aqA[2], aqB[2];
  aqA[0] = *(const short8*)(qpa + (size_t)n16 * H_DIM + quad * 8);
  aqA[1] = *(const short8*)(qpa + (size_t)n16 * H_DIM + 32 + quad * 8);
  aqB[0] = *(const short8*)(qpb + (size_t)n16 * H_DIM + quad * 8);
  aqB[1] = *(const short8*)(qpb + (size_t)n16 * H_DIM + 32 + quad * 8);

  f32x4 OA[4], OB[4];
#pragma unroll
  for (int i = 0; i < 4; ++i) {
    OA[i] = (f32x4){0.f, 0.f, 0.f, 0.f};
    OB[i] = (f32x4){0.f, 0.f, 0.f, 0.f};
  }
  float lsA[4] = {0.f, 0.f, 0.f, 0.f};
  float lsB[4] = {0.f, 0.f, 0.f, 0.f};

  const int nj = (r0b + 79) >> 6;   // j-tiles of 64 for the high tile
  const int njA = (r0a + 79) >> 6;  // j-tiles needed by the low tile

  for (int jt = ph; jt < nj; jt += PH) {
    const int j0 = jt * 64;
    const bool actA = (jt < njA);  // wave-uniform

    // K loads (needed first), then V loads (consumed ~600cy later at PV --
    // their L2 latency hides under QK MFMAs + exp/pack).
    short8 bk[4][2];
#pragma unroll
    for (int nt = 0; nt < 4; ++nt) {
      const short* kp = kb + (size_t)(j0 + nt * 16 + n16) * H_DIM + quad * 8;
      bk[nt][0] = *(const short8*)kp;
      bk[nt][1] = *(const short8*)(kp + 32);
    }
    short8 bv[4][2];
#pragma unroll
    for (int ht = 0; ht < 4; ++ht)
#pragma unroll
      for (int kh = 0; kh < 2; ++kh)
        bv[ht][kh] = *(const short8*)(vb + (size_t)(ht * 16 + n16) * T_SEQ +
                                      j0 + kh * 32 + quad * 8);

    // --- QK + exp/pack, tile B ---
    f32x4 sB[4];
#pragma unroll
    for (int nt = 0; nt < 4; ++nt) {
      f32x4 z = (f32x4){0.f, 0.f, 0.f, 0.f};
      z = __builtin_amdgcn_mfma_f32_16x16x32_bf16(aqB[0], bk[nt][0], z, 0, 0, 0);
      z = __builtin_amdgcn_mfma_f32_16x16x32_bf16(aqB[1], bk[nt][1], z, 0, 0, 0);
      sB[nt] = z;
    }
    const bool fullB = (j0 + 64 <= r0b);
#pragma unroll
    for (int nt = 0; nt < 4; ++nt) {
      const int base =
          (nt >> 1) * 512 + ((((nt & 1) << 1) | (n16 >> 3)) * 128) + (n16 & 7);
#pragma unroll
      for (int r = 0; r < 4; ++r) {
        float p;
        if (fullB) {
          p = __expf(sB[nt][r]);
        } else {
          const int j = j0 + nt * 16 + n16;
          const int row = r0b + quad * 4 + r;
          p = (j <= row) ? __expf(sB[nt][r]) : 0.f;
        }
        lsB[r] += p;
        pbuf[1024 + base + (quad * 4 + r) * 8] = f2bf(p);
      }
    }

    // --- QK + exp/pack, tile A (range is a subset of B's) ---
    if (actA) {
      f32x4 sA[4];
#pragma unroll
      for (int nt = 0; nt < 4; ++nt) {
        f32x4 z = (f32x4){0.f, 0.f, 0.f, 0.f};
        z = __builtin_amdgcn_mfma_f32_16x16x32_bf16(aqA[0], bk[nt][0], z, 0, 0, 0);
        z = __builtin_amdgcn_mfma_f32_16x16x32_bf16(aqA[1], bk[nt][1], z, 0, 0, 0);
        sA[nt] = z;
      }
      const bool fullA = (j0 + 64 <= r0a);
#pragma unroll
      for (int nt = 0; nt < 4; ++nt) {
        const int base =
            (nt >> 1) * 512 + ((((nt & 1) << 1) | (n16 >> 3)) * 128) + (n16 & 7);
#pragma unroll
        for (int r = 0; r < 4; ++r) {
          float p;
          if (fullA) {
            p = __expf(sA[nt][r]);
          } else {
            const int j = j0 + nt * 16 + n16;
            const int row = r0a + quad * 4 + r;
            p = (j <= row) ? __expf(sA[nt][r]) : 0.f;
          }
          lsA[r] += p;
          pbuf[base + (quad * 4 + r) * 8] = f2bf(p);
        }
      }
    }

    // --- PV ---
    const short8 apB0 = *(const short8*)(&pbuf[1024] + lane * 8);
    const short8 apB1 = *(const short8*)(&pbuf[1536] + lane * 8);
#pragma unroll
    for (int ht = 0; ht < 4; ++ht) {
      OB[ht] = __builtin_amdgcn_mfma_f32_16x16x32_bf16(apB0, bv[ht][0], OB[ht], 0, 0, 0);
      OB[ht] = __builtin_amdgcn_mfma_f32_16x16x32_bf16(apB1, bv[ht][1], OB[ht], 0, 0, 0);
    }
    if (actA) {
      const short8 apA0 = *(const short8*)(&pbuf[0] + lane * 8);
      const short8 apA1 = *(const short8*)(&pbuf[512] + lane * 8);
#pragma unroll
      for (int ht = 0; ht < 4; ++ht) {
        OA[ht] = __builtin_amdgcn_mfma_f32_16x16x32_bf16(apA0, bv[ht][0], OA[ht], 0, 0, 0);
        OA[ht] = __builtin_amdgcn_mfma_f32_16x16x32_bf16(apA1, bv[ht][1], OA[ht], 0, 0, 0);
      }
    }
  }

  // reduce lsum over the n16 group (rows are per (quad, r))
#pragma unroll
  for (int r = 0; r < 4; ++r) {
    float va = lsA[r], vb2 = lsB[r];
    va += __shfl_xor(va, 1);
    va += __shfl_xor(va, 2);
    va += __shfl_xor(va, 4);
    va += __shfl_xor(va, 8);
    vb2 += __shfl_xor(vb2, 1);
    vb2 += __shfl_xor(vb2, 2);
    vb2 += __shfl_xor(vb2, 4);
    vb2 += __shfl_xor(vb2, 8);
    lsA[r] = va;
    lsB[r] = vb2;
  }

  // write partials: O lane-linear (combine reads with identical indexing)
  float* opA = Opart + (size_t)blk * 2048;
  float* opB = opA + 1024;
#pragma unroll
  for (int ht = 0; ht < 4; ++ht)
#pragma unroll
    for (int r = 0; r < 4; ++r) {
      opA[(ht * 4 + r) * 64 + lane] = OA[ht][r];
      opB[(ht * 4 + r) * 64 + lane] = OB[ht][r];
    }
  if (n16 == 0) {
#pragma unroll
    for (int r = 0; r < 4; ++r) {
      lpart[blk * 32 + quad * 4 + r] = lsA[r];
      lpart[blk * 32 + 16 + quad * 4 + r] = lsB[r];
    }
  }
}

// ---------------------------------------------------------------------------
// K2b: combine the PH phase-partials and divide by the summed denominator.
// 1024 blocks x 128 thr: block = (b, pair pa, tile); the two waves split the
// 16 (ht,r) units.  Streaming ~29 MB -> memory-bound, ~6 us.
// ---------------------------------------------------------------------------
__global__ __launch_bounds__(128) void attn_comb(
    const float* __restrict__ Opart, const float* __restrict__ lpart,
    float* __restrict__ out) {
  const int tid = threadIdx.x;
  const int lane = tid & 63;
  const int half = tid >> 6;  // ht in {half*2, half*2+1}
  const int n16 = lane & 15, quad = lane >> 4;
  const int blk = blockIdx.x;
  const int b = blk & 7;
  const int tile = (blk >> 3) & 1;
  const int pa = blk >> 4;  // 0..63
  const int qt = tile ? (127 - pa) : pa;
  const int r0 = qt * 16;

  float acc[8];
#pragma unroll
  for (int u = 0; u < 8; ++u) acc[u] = 0.f;
  float ls[4] = {0.f, 0.f, 0.f, 0.f};

#pragma unroll
  for (int p2 = 0; p2 < PH; ++p2) {
    const int pblk = (pa * PH + p2) * 8 + b;
    const float* op =
        Opart + (size_t)pblk * 2048 + tile * 1024 + half * 512;
#pragma unroll
    for (int u = 0; u < 8; ++u) acc[u] += op[u * 64 + lane];
    const float* lp = lpart + pblk * 32 + tile * 16;
#pragma unroll
    for (int r = 0; r < 4; ++r) ls[r] += lp[quad * 4 + r];
  }

#pragma unroll
  for (int u = 0; u < 8; ++u) {
    const int ht = half * 2 + (u >> 2), r = u & 3;
    out[((size_t)b * T_SEQ + r0 + quad * 4 + r) * H_DIM + ht * 16 + n16] =
        acc[u] / ls[r];
  }
}

extern "C" void kernel_launch(void* const* d_in, const int* in_sizes, int n_in,
                              void* d_out, int out_size, void* d_ws,
                              size_t ws_size, hipStream_t stream) {
  const float* x = (const float*)d_in[0];
  const float* Wq = (const float*)d_in[1];
  const float* Wk = (const float*)d_in[2];
  const float* Wv = (const float*)d_in[3];

  char* ws = (char*)d_ws;
  short* Wt = (short*)ws;                       // 384 KB (fragment-linear)
  short* q = (short*)(ws + 393216);             // 2 MB each
  short* kk = (short*)(ws + 393216 + 2097152);
  short* vt = (short*)(ws + 393216 + 2 * 2097152);
  float* Opart = (float*)(ws + 6684672);        // 3072 x 2048 fp32 = 24 MB
  float* lpart = (float*)(ws + 6684672 + 25165824);  // 3072 x 32 fp32

  w_prep<<<96, 256, 0, stream>>>(Wq, Wk, Wv, Wt);
  qkv_gemm<<<NROW / 32, 256, 0, stream>>>(x, Wt, q, kk, vt);
  attn_part<<<64 * PH * 8, 64, 0, stream>>>(q, kk, vt, Opart, lpart);
  attn_comb<<<64 * 2 * 8, 128, 0, stream>>>(Opart, lpart, (float*)d_out);
}

// Round 5
// 140.495 us; speedup vs baseline: 1.0568x; 1.0198x over previous
//
#include <hip/hip_runtime.h>

#define T_SEQ 2048
#define C_DIM 1024
#define H_DIM 64
#define B_DIM 8
#define NROW (B_DIM * T_SEQ)  // 16384

typedef __attribute__((ext_vector_type(8))) short short8;
typedef __attribute__((ext_vector_type(4))) float f32x4;

__device__ __forceinline__ short f2bf(float f) {
  unsigned u = __builtin_bit_cast(unsigned, f);
  u += 0x7fffu + ((u >> 16) & 1u);  // round-to-nearest-even
  return (short)(u >> 16);
}

// ---------------------------------------------------------------------------
// P: Wt2 in FRAGMENT-LINEAR order (unchanged).
// ---------------------------------------------------------------------------
__global__ __launch_bounds__(256) void w_prep(
    const float* __restrict__ Wq, const float* __restrict__ Wk,
    const float* __restrict__ Wv, short* __restrict__ Wt2) {
  const int unit = blockIdx.x * 256 + threadIdx.x;  // 0..24575
  const int lane = unit & 63;
  const int t = unit >> 6;
  const int kh = t & 3;
  const int g = t >> 2;    // kc*12 + ntg
  const int ntg = g % 12;
  const int kc = g / 12;
  const int n16 = lane & 15, quad = lane >> 4;
  const int mat = ntg >> 2;
  const int h = (ntg & 3) * 16 + n16;
  const int kb = kc * 128 + kh * 32 + quad * 8;
  const float* W = (mat == 0) ? Wq : (mat == 1 ? Wk : Wv);
  short8 v;
#pragma unroll
  for (int e = 0; e < 8; ++e) v[e] = f2bf(W[(size_t)(kb + e) * H_DIM + h]);
  *(short8*)(Wt2 + (size_t)unit * 8) = v;
}

// LDS address (in shorts) for A frag unit (tile, kh, quad, n16); XOR-swizzled.
__device__ __forceinline__ int lds_addr(int tile, int kh, int qd, int nn) {
  return tile * 2048 + kh * 512 + (qd * 16 + (nn ^ ((kh * 4 + qd) & 7))) * 8;
}

// ---------------------------------------------------------------------------
// K1: QKV projection (byte-identical -- at its structural/HBM bound).
// ---------------------------------------------------------------------------
__global__ __launch_bounds__(256, 2) void qkv_gemm(
    const float* __restrict__ x, const short* __restrict__ Wt2,
    short* __restrict__ q, short* __restrict__ k, short* __restrict__ vt) {
  __shared__ __align__(16) short As[2][4096];  // 2 x 8 KB (32 x 128 bf16)
  const int tid = threadIdx.x;
  const int w = tid >> 6, lane = tid & 63;
  const int n16 = lane & 15, quad = lane >> 4;
  const int row0 = blockIdx.x * 32;

  f32x4 acc[2][3];
#pragma unroll
  for (int mt = 0; mt < 2; ++mt)
#pragma unroll
    for (int ln = 0; ln < 3; ++ln) acc[mt][ln] = (f32x4){0.f, 0.f, 0.f, 0.f};

  const int u20 = tid, u21 = 256 + tid;
  const int sr0 = u20 >> 4, f0 = u20 & 15;
  const int sr1 = u21 >> 4, f1 = u21 & 15;
  const float* ap0 = x + (size_t)(row0 + sr0) * C_DIM + f0 * 8;
  const float* ap1 = x + (size_t)(row0 + sr1) * C_DIM + f1 * 8;
  const int soff0 = lds_addr(sr0 >> 4, f0 >> 2, f0 & 3, sr0 & 15);
  const int soff1 = lds_addr(sr1 >> 4, f1 >> 2, f1 & 3, sr1 & 15);

  int swz[4];
#pragma unroll
  for (int kh = 0; kh < 4; ++kh)
    swz[kh] = (quad * 16 + (n16 ^ ((kh * 4 + quad) & 7))) * 8;

  const short* bbase = Wt2 + (size_t)(w * 3) * 2048 + (size_t)lane * 8;

  float4 astg[2][4];
  short8 bfr[12];

#define STAGE_A(d, p)                                      \
  {                                                        \
    short8 av0, av1;                                       \
    _Pragma("unroll") for (int e = 0; e < 4; ++e) {        \
      av0[e] = f2bf(((const float*)&astg[d][0])[e]);       \
      av0[e + 4] = f2bf(((const float*)&astg[d][1])[e]);   \
      av1[e] = f2bf(((const float*)&astg[d][2])[e]);       \
      av1[e + 4] = f2bf(((const float*)&astg[d][3])[e]);   \
    }                                                      \
    *(short8*)(&As[p][0] + soff0) = av0;                   \
    *(short8*)(&As[p][0] + soff1) = av1;                   \
  }

  astg[0][0] = *(const float4*)(ap0);
  astg[0][1] = *(const float4*)(ap0 + 4);
  astg[0][2] = *(const float4*)(ap1);
  astg[0][3] = *(const float4*)(ap1 + 4);
  astg[1][0] = *(const float4*)(ap0 + 128);
  astg[1][1] = *(const float4*)(ap0 + 132);
  astg[1][2] = *(const float4*)(ap1 + 128);
  astg[1][3] = *(const float4*)(ap1 + 132);
#pragma unroll
  for (int ln = 0; ln < 3; ++ln)
#pragma unroll
    for (int kh = 0; kh < 4; ++kh)
      bfr[ln * 4 + kh] = *(const short8*)(bbase + ln * 2048 + kh * 512);
  STAGE_A(0, 0);
  asm volatile("s_waitcnt lgkmcnt(0)" ::: "memory");
  __builtin_amdgcn_sched_barrier(0);
  __builtin_amdgcn_s_barrier();
  __builtin_amdgcn_sched_barrier(0);

#pragma unroll
  for (int kc = 0; kc < 8; ++kc) {
    const short* asb = &As[kc & 1][0];
#pragma unroll
    for (int kh = 0; kh < 4; ++kh) {
      const short8 a0 = *(const short8*)(asb + kh * 512 + swz[kh]);
      const short8 a1 = *(const short8*)(asb + 2048 + kh * 512 + swz[kh]);
#pragma unroll
      for (int ln = 0; ln < 3; ++ln) {
        acc[0][ln] = __builtin_amdgcn_mfma_f32_16x16x32_bf16(
            a0, bfr[ln * 4 + kh], acc[0][ln], 0, 0, 0);
        acc[1][ln] = __builtin_amdgcn_mfma_f32_16x16x32_bf16(
            a1, bfr[ln * 4 + kh], acc[1][ln], 0, 0, 0);
      }
    }
    if (kc < 7) {
      const short* bc = bbase + (size_t)(kc + 1) * 24576;
#pragma unroll
      for (int ln = 0; ln < 3; ++ln)
#pragma unroll
        for (int kh = 0; kh < 4; ++kh)
          bfr[ln * 4 + kh] = *(const short8*)(bc + ln * 2048 + kh * 512);
      if (kc < 6) {
        astg[kc & 1][0] = *(const float4*)(ap0 + (kc + 2) * 128);
        astg[kc & 1][1] = *(const float4*)(ap0 + (kc + 2) * 128 + 4);
        astg[kc & 1][2] = *(const float4*)(ap1 + (kc + 2) * 128);
        astg[kc & 1][3] = *(const float4*)(ap1 + (kc + 2) * 128 + 4);
      }
      STAGE_A((kc + 1) & 1, (kc + 1) & 1);
      asm volatile("s_waitcnt lgkmcnt(0)" ::: "memory");
      __builtin_amdgcn_sched_barrier(0);
      __builtin_amdgcn_s_barrier();
      __builtin_amdgcn_sched_barrier(0);
    }
  }
#undef STAGE_A

  const int b = row0 >> 11;
#pragma unroll
  for (int mt = 0; mt < 2; ++mt)
#pragma unroll
    for (int ln = 0; ln < 3; ++ln) {
      const int ntg = w * 3 + ln;
      const int mat = ntg >> 2;
      const int cl = (ntg & 3) * 16 + n16;
#pragma unroll
      for (int r = 0; r < 4; ++r) {
        const int row = row0 + mt * 16 + quad * 4 + r;
        const float v = acc[mt][ln][r];
        if (mat == 0)
          q[(size_t)row * H_DIM + cl] = f2bf(v * 0.125f);
        else if (mat == 1)
          k[(size_t)row * H_DIM + cl] = f2bf(v);
        else
          vt[((size_t)b * H_DIM + cl) * T_SEQ + (row & (T_SEQ - 1))] = f2bf(v);
      }
    }
}

// ---------------------------------------------------------------------------
// K2: paired-tile flash attention (R2 structure, best so far) + spill-free
// latency hiding.  Vs R2: (a) V loads issued at ITERATION TOP (~500cy before
// PV consumes them, hidden under QK+exp/pack); (b) K register double-buffer,
// next iter's K issued right after current QK MFMAs (~700cy cover).  Vs R3:
// NO launch_bounds min-waves cap (R3's (256,2) forced a 128-VGPR ceiling ->
// ~13MB scratch spills, the regression).  Natural peak ~200 VGPR -> no spill,
// same 2 blocks/CU occupancy as R2.  Same jt%4==w partition and accumulation
// order -> absmax bit-identical.
// ---------------------------------------------------------------------------
__global__ __launch_bounds__(256) void attn_mfma(
    const short* __restrict__ q, const short* __restrict__ k,
    const short* __restrict__ vt, float* __restrict__ out) {
  __shared__ __align__(16) short pbuf[4][2048];    // per-wave: A | B
  __shared__ __align__(16) float oshare[3][2048];  // A | B
  __shared__ __align__(16) float lshare[3][512];   // A | B
  const int tid = threadIdx.x;
  const int w = tid >> 6;
  const int lane = tid & 63;
  const int n16 = lane & 15, quad = lane >> 4;
  const int b = blockIdx.x & 7;     // b == XCD slot -> K/V L2-resident
  const int pa = blockIdx.x >> 3;   // 0..63
  const int r0a = pa * 16;          // low tile rows
  const int r0b = (127 - pa) * 16;  // high tile rows

  const short* kb = k + (size_t)b * T_SEQ * H_DIM;
  const short* vb = vt + (size_t)b * H_DIM * T_SEQ;
  const short* qpa = q + ((size_t)b * T_SEQ + r0a) * H_DIM;
  const short* qpb = q + ((size_t)b * T_SEQ + r0b) * H_DIM;

  short8 aqA[2], aqB[2];
  aqA[0] = *(const short8*)(qpa + (size_t)n16 * H_DIM + quad * 8);
  aqA[1] = *(const short8*)(qpa + (size_t)n16 * H_DIM + 32 + quad * 8);
  aqB[0] = *(const short8*)(qpb + (size_t)n16 * H_DIM + quad * 8);
  aqB[1] = *(const short8*)(qpb + (size_t)n16 * H_DIM + 32 + quad * 8);

  f32x4 OA[4], OB[4];
#pragma unroll
  for (int i = 0; i < 4; ++i) {
    OA[i] = (f32x4){0.f, 0.f, 0.f, 0.f};
    OB[i] = (f32x4){0.f, 0.f, 0.f, 0.f};
  }
  float lsA[4] = {0.f, 0.f, 0.f, 0.f};
  float lsB[4] = {0.f, 0.f, 0.f, 0.f};

  const int nj = (r0b + 79) >> 6;   // j-tiles of 64 for the high tile
  const int njA = (r0a + 79) >> 6;  // j-tiles needed by the low tile

  short8 bk0[4][2], bk1[4][2];

#define LOADK(BK, J0)                                                         \
  _Pragma("unroll") for (int nt = 0; nt < 4; ++nt) {                          \
    const short* kp = kb + (size_t)((J0) + nt * 16 + n16) * H_DIM + quad * 8; \
    BK[nt][0] = *(const short8*)kp;                                           \
    BK[nt][1] = *(const short8*)(kp + 32);                                    \
  }

// one j-iteration: consume K from BKC; prefetch K(JN) into BKN.
#define DOITER(BKC, BKN, JT, JN)                                              \
  {                                                                           \
    const int j0 = (JT) * 64;                                                 \
    const bool actA = ((JT) < njA);                                           \
    /* V issued first: consumed by PV ~500cy later (hidden under QK+exp) */   \
    short8 bv[4][2];                                                          \
    _Pragma("unroll") for (int ht = 0; ht < 4; ++ht)                          \
    _Pragma("unroll") for (int kh = 0; kh < 2; ++kh)                          \
        bv[ht][kh] = *(const short8*)(vb + (size_t)(ht * 16 + n16) * T_SEQ +  \
                                      j0 + kh * 32 + quad * 8);               \
    f32x4 sB[4];                                                              \
    _Pragma("unroll") for (int nt = 0; nt < 4; ++nt) {                        \
      f32x4 z = (f32x4){0.f, 0.f, 0.f, 0.f};                                  \
      z = __builtin_amdgcn_mfma_f32_16x16x32_bf16(aqB[0], BKC[nt][0], z, 0, 0, 0); \
      z = __builtin_amdgcn_mfma_f32_16x16x32_bf16(aqB[1], BKC[nt][1], z, 0, 0, 0); \
      sB[nt] = z;                                                             \
    }                                                                         \
    f32x4 sA[4];                                                              \
    if (actA) {                                                               \
      _Pragma("unroll") for (int nt = 0; nt < 4; ++nt) {                      \
        f32x4 z = (f32x4){0.f, 0.f, 0.f, 0.f};                                \
        z = __builtin_amdgcn_mfma_f32_16x16x32_bf16(aqA[0], BKC[nt][0], z, 0, 0, 0); \
        z = __builtin_amdgcn_mfma_f32_16x16x32_bf16(aqA[1], BKC[nt][1], z, 0, 0, 0); \
        sA[nt] = z;                                                           \
      }                                                                       \
    }                                                                         \
    /* prefetch next iter's K now: latency hides under exp/pack + PV */       \
    if ((JN) < nj) { LOADK(BKN, (JN) * 64); }                                 \
    const bool fullB = (j0 + 64 <= r0b);                                      \
    _Pragma("unroll") for (int nt = 0; nt < 4; ++nt) {                        \
      const int base = (nt >> 1) * 512 +                                      \
                       ((((nt & 1) << 1) | (n16 >> 3)) * 128) + (n16 & 7);    \
      _Pragma("unroll") for (int r = 0; r < 4; ++r) {                         \
        float p;                                                              \
        if (fullB) {                                                          \
          p = __expf(sB[nt][r]);                                              \
        } else {                                                              \
          const int j = j0 + nt * 16 + n16;                                   \
          const int row = r0b + quad * 4 + r;                                 \
          p = (j <= row) ? __expf(sB[nt][r]) : 0.f;                           \
        }                                                                     \
        lsB[r] += p;                                                          \
        pbuf[w][1024 + base + (quad * 4 + r) * 8] = f2bf(p);                  \
      }                                                                       \
    }                                                                         \
    if (actA) {                                                               \
      const bool fullA = (j0 + 64 <= r0a);                                    \
      _Pragma("unroll") for (int nt = 0; nt < 4; ++nt) {                      \
        const int base = (nt >> 1) * 512 +                                    \
                         ((((nt & 1) << 1) | (n16 >> 3)) * 128) + (n16 & 7);  \
        _Pragma("unroll") for (int r = 0; r < 4; ++r) {                       \
          float p;                                                            \
          if (fullA) {                                                        \
            p = __expf(sA[nt][r]);                                            \
          } else {                                                            \
            const int j = j0 + nt * 16 + n16;                                 \
            const int row = r0a + quad * 4 + r;                               \
            p = (j <= row) ? __expf(sA[nt][r]) : 0.f;                         \
          }                                                                   \
          lsA[r] += p;                                                        \
          pbuf[w][base + (quad * 4 + r) * 8] = f2bf(p);                       \
        }                                                                     \
      }                                                                       \
    }                                                                         \
    const short8 apB0 = *(const short8*)(&pbuf[w][1024] + lane * 8);          \
    const short8 apB1 = *(const short8*)(&pbuf[w][1536] + lane * 8);          \
    _Pragma("unroll") for (int ht = 0; ht < 4; ++ht) {                        \
      OB[ht] = __builtin_amdgcn_mfma_f32_16x16x32_bf16(apB0, bv[ht][0], OB[ht], 0, 0, 0); \
      OB[ht] = __builtin_amdgcn_mfma_f32_16x16x32_bf16(apB1, bv[ht][1], OB[ht], 0, 0, 0); \
    }                                                                         \
    if (actA) {                                                               \
      const short8 apA0 = *(const short8*)(&pbuf[w][0] + lane * 8);           \
      const short8 apA1 = *(const short8*)(&pbuf[w][512] + lane * 8);         \
      _Pragma("unroll") for (int ht = 0; ht < 4; ++ht) {                      \
        OA[ht] = __builtin_amdgcn_mfma_f32_16x16x32_bf16(apA0, bv[ht][0], OA[ht], 0, 0, 0); \
        OA[ht] = __builtin_amdgcn_mfma_f32_16x16x32_bf16(apA1, bv[ht][1], OA[ht], 0, 0, 0); \
      }                                                                       \
    }                                                                         \
  }

  // prologue: first K tile (only exposed K-latency wait of the whole loop)
  LOADK(bk0, w * 64);
  for (int jt = w; jt < nj; jt += 8) {
    const int jB = jt + 4;
    DOITER(bk0, bk1, jt, jB);
    if (jB < nj) {
      DOITER(bk1, bk0, jB, jt + 8);
    }
  }
#undef DOITER
#undef LOADK

  // --- cross-wave reduction (unchanged from R2) ---
  if (w != 0) {
#pragma unroll
    for (int ht = 0; ht < 4; ++ht)
#pragma unroll
      for (int r = 0; r < 4; ++r) {
        oshare[w - 1][(ht * 4 + r) * 64 + lane] = OA[ht][r];
        oshare[w - 1][1024 + (ht * 4 + r) * 64 + lane] = OB[ht][r];
      }
#pragma unroll
    for (int r = 0; r < 4; ++r) {
      lshare[w - 1][r * 64 + lane] = lsA[r];
      lshare[w - 1][256 + r * 64 + lane] = lsB[r];
    }
  }
  __syncthreads();
  if (w == 0) {
#pragma unroll
    for (int ht = 0; ht < 4; ++ht)
#pragma unroll
      for (int r = 0; r < 4; ++r) {
        float a = OA[ht][r], bb = OB[ht][r];
#pragma unroll
        for (int ow = 0; ow < 3; ++ow) {
          a += oshare[ow][(ht * 4 + r) * 64 + lane];
          bb += oshare[ow][1024 + (ht * 4 + r) * 64 + lane];
        }
        OA[ht][r] = a;
        OB[ht][r] = bb;
      }
#pragma unroll
    for (int r = 0; r < 4; ++r) {
      float va = lsA[r], vb2 = lsB[r];
#pragma unroll
      for (int ow = 0; ow < 3; ++ow) {
        va += lshare[ow][r * 64 + lane];
        vb2 += lshare[ow][256 + r * 64 + lane];
      }
      va += __shfl_xor(va, 1);
      va += __shfl_xor(va, 2);
      va += __shfl_xor(va, 4);
      va += __shfl_xor(va, 8);
      vb2 += __shfl_xor(vb2, 1);
      vb2 += __shfl_xor(vb2, 2);
      vb2 += __shfl_xor(vb2, 4);
      vb2 += __shfl_xor(vb2, 8);
      lsA[r] = va;
      lsB[r] = vb2;
    }
#pragma unroll
    for (int ht = 0; ht < 4; ++ht)
#pragma unroll
      for (int r = 0; r < 4; ++r) {
        out[((size_t)b * T_SEQ + r0a + quad * 4 + r) * H_DIM + ht * 16 + n16] =
            OA[ht][r] / lsA[r];
        out[((size_t)b * T_SEQ + r0b + quad * 4 + r) * H_DIM + ht * 16 + n16] =
            OB[ht][r] / lsB[r];
      }
  }
}

extern "C" void kernel_launch(void* const* d_in, const int* in_sizes, int n_in,
                              void* d_out, int out_size, void* d_ws,
                              size_t ws_size, hipStream_t stream) {
  const float* x = (const float*)d_in[0];
  const float* Wq = (const float*)d_in[1];
  const float* Wk = (const float*)d_in[2];
  const float* Wv = (const float*)d_in[3];

  char* ws = (char*)d_ws;
  short* Wt = (short*)ws;                       // 384 KB (fragment-linear)
  short* q = (short*)(ws + 3 * 64 * 1024 * 2);  // 2 MB each
  short* kk = (short*)(ws + 3 * 64 * 1024 * 2 + 2097152);
  short* vt = (short*)(ws + 3 * 64 * 1024 * 2 + 2 * 2097152);

  w_prep<<<96, 256, 0, stream>>>(Wq, Wk, Wv, Wt);
  qkv_gemm<<<NROW / 32, 256, 0, stream>>>(x, Wt, q, kk, vt);
  attn_mfma<<<B_DIM * (T_SEQ / 32), 256, 0, stream>>>(q, kk, vt, (float*)d_out);
}